// Round 6
// baseline (940.463 us; speedup 1.0000x reference)
//
#include <hip/hip_runtime.h>
#include <hip/hip_bf16.h>
#include <math.h>

// NODE_DIM=3, EMBED=16
#define ND 3
#define EM 16
#define BQ 512        // nodes per bucket (power of 2)
#define BQ_SH 9
#define MAXB 1024     // max buckets => supports N <= 524288
#define CHK 8192      // edges per edge_bin block (32 per thread)
#define COLS 12288    // LDS col staging bound (mean bucket edges ~8192, +45 sigma)
// packed pair: (dst & 511) << 23 | src   (requires src < 2^23)
#define P_SH 23

__device__ __forceinline__ float sp(float x) {
    // jax.nn.softplus = max(x,0) + log1p(exp(-|x|))
    return fmaxf(x, 0.0f) + log1pf(expf(-fabsf(x)));
}

// Kernel 0: zero bucket counters.
__global__ __launch_bounds__(1024) void bucket_zero(int* __restrict__ bcnt)
{
    bcnt[threadIdx.x] = 0;
}

// Kernel A: bucket histogram of dst (bucket = dst >> 9). ONE pass over dst
// (32MB), LDS-aggregated, ~1k global atomics per block.
__global__ __launch_bounds__(256) void bucket_count(
    const int* __restrict__ ei, int* __restrict__ bcnt, int E, int NB)
{
    __shared__ int h[MAXB];
    int t = threadIdx.x;
    for (int i = t; i < MAXB; i += 256) h[i] = 0;
    __syncthreads();
    const int* dp = ei + (size_t)E;
    for (int e = blockIdx.x * 256 + t; e < E; e += gridDim.x * 256)
        atomicAdd(&h[((unsigned)dp[e]) >> BQ_SH], 1);
    __syncthreads();
    for (int i = t; i < NB; i += 256) {
        int v = h[i];
        if (v) atomicAdd(&bcnt[i], v);
    }
}

// Kernel B: exclusive scan of bucket counts (NB <= 1024) -> gbase, gcur.
__global__ __launch_bounds__(1024) void bucket_scan(
    const int* __restrict__ bcnt, int* __restrict__ gbase,
    int* __restrict__ gcur, int NB)
{
    __shared__ int sd[1024];
    int t = threadIdx.x;
    int v = (t < NB) ? bcnt[t] : 0;
    sd[t] = v;
    __syncthreads();
    for (int off = 1; off < 1024; off <<= 1) {
        int add = (t >= off) ? sd[t - off] : 0;
        __syncthreads();
        sd[t] += add;
        __syncthreads();
    }
    if (t < NB) { int ex = sd[t] - v; gbase[t] = ex; gcur[t] = ex; }
}

// Kernel C: bin edges into bucket-contiguous packed-pair runs, with the
// chunk SORTED IN LDS first so global writes are in-order & coalesced.
__global__ __launch_bounds__(256) void edge_bin(
    const int* __restrict__ ei, int* __restrict__ gcur,
    unsigned int* __restrict__ pairs, int E)
{
    __shared__ int lcnt[MAXB];            // histogram, then local cursor
    __shared__ int lbase[MAXB];           // local exclusive base
    __shared__ int sbase[MAXB];           // global run base
    __shared__ unsigned int stage[CHK];   // bucket-sorted packed payloads
    __shared__ unsigned short bid[CHK];   // bucket id per staged slot
    __shared__ int sd[256];
    int t = threadIdx.x;
    int c0 = blockIdx.x * CHK;
    int cntT = min(CHK, E - c0);
    for (int i = t; i < MAXB; i += 256) lcnt[i] = 0;
    __syncthreads();
    const int* dp = ei + (size_t)E;
    int dreg[32];
#pragma unroll
    for (int it = 0; it < 32; it++) {
        int e = c0 + it * 256 + t;
        dreg[it] = (e < E) ? dp[e] : 0;
        if (e < E) atomicAdd(&lcnt[((unsigned)dreg[it]) >> BQ_SH], 1);
    }
    __syncthreads();
    // exclusive scan of lcnt[1024] (4 per thread) -> lbase; reserve runs.
    int b4 = t * 4;
    int h0 = lcnt[b4], h1 = lcnt[b4 + 1], h2 = lcnt[b4 + 2], h3 = lcnt[b4 + 3];
    int s4 = h0 + h1 + h2 + h3;
    sd[t] = s4;
    __syncthreads();
    for (int off = 1; off < 256; off <<= 1) {
        int add = (t >= off) ? sd[t - off] : 0;
        __syncthreads();
        sd[t] += add;
        __syncthreads();
    }
    int ex = sd[t] - s4;
    lbase[b4]     = ex;
    lbase[b4 + 1] = ex + h0;
    lbase[b4 + 2] = ex + h0 + h1;
    lbase[b4 + 3] = ex + h0 + h1 + h2;
    sbase[b4]     = h0 ? atomicAdd(&gcur[b4], h0)     : 0;
    sbase[b4 + 1] = h1 ? atomicAdd(&gcur[b4 + 1], h1) : 0;
    sbase[b4 + 2] = h2 ? atomicAdd(&gcur[b4 + 2], h2) : 0;
    sbase[b4 + 3] = h3 ? atomicAdd(&gcur[b4 + 3], h3) : 0;
    lcnt[b4] = 0; lcnt[b4 + 1] = 0; lcnt[b4 + 2] = 0; lcnt[b4 + 3] = 0;
    __syncthreads();
    // scatter into LDS stage (bucket-sorted order)
#pragma unroll
    for (int it = 0; it < 32; it++) {
        int e = c0 + it * 256 + t;
        if (e < E) {
            int d = dreg[it];
            unsigned b = ((unsigned)d) >> BQ_SH;
            int s = ei[e];
            int pos = lbase[b] + atomicAdd(&lcnt[b], 1);
            stage[pos] = ((unsigned)(d & (BQ - 1)) << P_SH) | (unsigned)s;
            bid[pos] = (unsigned short)b;
        }
    }
    __syncthreads();
    // in-order write-out: consecutive threads -> consecutive addresses
    for (int i = t; i < cntT; i += 256) {
        unsigned b = bid[i];
        pairs[sbase[b] + (i - lbase[b])] = stage[i];
    }
}

// Kernel D: per-bucket CSR build. Writes src into cw[].x (weight slot .y is
// filled later by deg_gather). One block per bucket: LDS per-node histogram
// -> LDS scan -> rowptr slice (coalesced); scatter src into LDS staging via
// LDS atomics; flush cw.x in index order.
__global__ __launch_bounds__(256) void bucket_csr(
    const unsigned int* __restrict__ pairs, const int* __restrict__ gbase,
    const int* __restrict__ bcnt, int* __restrict__ rowptr,
    int2* __restrict__ cw, int N, int NB)
{
    __shared__ int ncnt[BQ];
    __shared__ int ncur[BQ];
    __shared__ int sd[256];
    __shared__ int colS[COLS];
    int b = blockIdx.x;
    int t = threadIdx.x;
    int lo = b << BQ_SH;
    int hi = min(lo + BQ, N);
    int r0 = gbase[b];
    int cntE = bcnt[b];
    ncnt[2 * t] = 0;
    ncnt[2 * t + 1] = 0;
    __syncthreads();
    for (int i = t; i < cntE; i += 256)
        atomicAdd(&ncnt[pairs[r0 + i] >> P_SH], 1);
    __syncthreads();
    // exclusive scan over 512 (2 per thread)
    int a0 = ncnt[2 * t], a1 = ncnt[2 * t + 1];
    int s2 = a0 + a1;
    sd[t] = s2;
    __syncthreads();
    for (int off = 1; off < 256; off <<= 1) {
        int add = (t >= off) ? sd[t - off] : 0;
        __syncthreads();
        sd[t] += add;
        __syncthreads();
    }
    int ex = sd[t] - s2;          // exclusive base for node 2t
    ncur[2 * t] = ex;
    ncur[2 * t + 1] = ex + a0;
    if (lo + 2 * t < hi)     rowptr[lo + 2 * t]     = r0 + ex;
    if (lo + 2 * t + 1 < hi) rowptr[lo + 2 * t + 1] = r0 + ex + a0;
    if (b == NB - 1 && t == 0) rowptr[N] = r0 + cntE;  // == E
    __syncthreads();
    bool fit = (cntE <= COLS);
    for (int i = t; i < cntE; i += 256) {
        unsigned p = pairs[r0 + i];
        int slot = atomicAdd(&ncur[p >> P_SH], 1);
        int srcv = (int)(p & ((1u << P_SH) - 1));
        if (fit) colS[slot] = srcv;
        else     cw[r0 + slot].x = srcv;
    }
    __syncthreads();
    if (fit)
        for (int i = t; i < cntE; i += 256) cw[r0 + i].x = colS[i];
}

// Kernel 1: x0 = softplus(pos @ W_init + b_init); xwA = x0 @ W_g1.
__global__ __launch_bounds__(256) void node_init(
    const float* __restrict__ pos,
    const float* __restrict__ W_init, const float* __restrict__ b_init,
    const float* __restrict__ W_g1,
    float* __restrict__ xw, int N)
{
    __shared__ float sWi[ND * EM];
    __shared__ float sbi[EM];
    __shared__ float sW1[EM * EM];
    int t = threadIdx.x;
    if (t < ND * EM) sWi[t] = W_init[t];
    if (t < EM)      sbi[t] = b_init[t];
    sW1[t] = W_g1[t];
    __syncthreads();

    int n = blockIdx.x * 256 + t;
    if (n >= N) return;

    float p0 = pos[3 * (size_t)n + 0];
    float p1 = pos[3 * (size_t)n + 1];
    float p2 = pos[3 * (size_t)n + 2];

    float x0[EM];
#pragma unroll
    for (int j = 0; j < EM; j++) {
        float h = fmaf(p0, sWi[0 * EM + j],
                  fmaf(p1, sWi[1 * EM + j],
                  fmaf(p2, sWi[2 * EM + j], sbi[j])));
        x0[j] = sp(h);
    }
    float o[EM];
#pragma unroll
    for (int k = 0; k < EM; k++) {
        float a = 0.0f;
#pragma unroll
        for (int j = 0; j < EM; j++) a = fmaf(x0[j], sW1[j * EM + k], a);
        o[k] = a;
    }
    float4* xo = (float4*)(xw + (size_t)n * EM);
#pragma unroll
    for (int q = 0; q < 4; q++)
        xo[q] = make_float4(o[4*q+0], o[4*q+1], o[4*q+2], o[4*q+3]);
}

// Kernel 5: weighted degree via gather; dinv = rsqrt(1 + sum_w).
// Reads src from cw[].x, writes weight into cw[].y (same lines -> good L2
// locality); scales xwA row in place by dinv[n].
__global__ __launch_bounds__(256) void deg_gather(
    const int* __restrict__ rowptr, int2* __restrict__ cw,
    const float* __restrict__ pos, float* __restrict__ dinv,
    float* __restrict__ xw, int N)
{
    int t = threadIdx.x;
    int lane = t & 15;
    int n = blockIdx.x * 16 + (t >> 4);
    if (n >= N) return;
    int start = rowptr[n], end = rowptr[n + 1];
    float px = pos[3 * (size_t)n + 0];
    float py = pos[3 * (size_t)n + 1];
    float pz = pos[3 * (size_t)n + 2];
    float sum = 0.0f;
    for (int j = start + lane; j < end; j += 16) {
        int s = cw[j].x;
        float dx = px - pos[3 * (size_t)s + 0];
        float dy = py - pos[3 * (size_t)s + 1];
        float dz = pz - pos[3 * (size_t)s + 2];
        float d = sqrtf(fmaf(dx, dx, fmaf(dy, dy, dz * dz)));
        cw[j].y = __float_as_int(d);
        sum += d;
    }
#pragma unroll
    for (int off = 8; off >= 1; off >>= 1) sum += __shfl_xor(sum, off, 64);
    float di = rsqrtf(1.0f + sum);
    if (lane == 0) dinv[n] = di;
    xw[(size_t)n * EM + lane] *= di;   // z1 = dinv * xwA (coalesced 64B row)
}

// Kernel 6 (x2): fused GCN-mean layer. 8 lanes/node (lane = channel PAIR),
// 32 nodes per 256-thread block -> 2x the concurrent node streams for
// latency hiding. Per edge: ONE int2 cw load + ONE float2 z load per lane.
// acc += w*z2[src]; self loop = z2[n]; x = sp(di*acc/(deg+1)+b).
// If mulW: out = (x @ W) * di (pre-scales next layer's z).
__global__ __launch_bounds__(256) void gather_conv(
    const int* __restrict__ rowptr, const int2* __restrict__ cw,
    const float* __restrict__ dinv, const float* __restrict__ z,
    const float* __restrict__ bconv, const float* __restrict__ W,
    float* __restrict__ xout, int N, int mulW)
{
    __shared__ float sW[EM * EM];
    __shared__ float lx[32][EM + 1];
    int t = threadIdx.x;
    sW[t] = W[t];
    int g = t >> 3, c = t & 7;          // 32 node groups, 8 lanes each
    int n = blockIdx.x * 32 + g;

    float xx = 0.0f, xy = 0.0f;
    float di = 1.0f;
    if (n < N) {
        int start = rowptr[n], end = rowptr[n + 1];
        di = dinv[n];
        const float2* zs = (const float2*)(z + (size_t)n * EM) + c;
        float2 zv = *zs;                 // self loop (pre-scaled)
        float a0x = zv.x, a0y = zv.y;
        float a1x = 0.f, a1y = 0.f, a2x = 0.f, a2y = 0.f, a3x = 0.f, a3y = 0.f;
        int j = start;
        for (; j + 3 < end; j += 4) {
            int2 e0 = cw[j], e1 = cw[j + 1], e2 = cw[j + 2], e3 = cw[j + 3];
            float2 z0 = *((const float2*)(z + (size_t)e0.x * EM) + c);
            float2 z1 = *((const float2*)(z + (size_t)e1.x * EM) + c);
            float2 z2 = *((const float2*)(z + (size_t)e2.x * EM) + c);
            float2 z3 = *((const float2*)(z + (size_t)e3.x * EM) + c);
            float w0 = __int_as_float(e0.y), w1 = __int_as_float(e1.y);
            float w2 = __int_as_float(e2.y), w3 = __int_as_float(e3.y);
            a0x = fmaf(w0, z0.x, a0x); a0y = fmaf(w0, z0.y, a0y);
            a1x = fmaf(w1, z1.x, a1x); a1y = fmaf(w1, z1.y, a1y);
            a2x = fmaf(w2, z2.x, a2x); a2y = fmaf(w2, z2.y, a2y);
            a3x = fmaf(w3, z3.x, a3x); a3y = fmaf(w3, z3.y, a3y);
        }
        for (; j < end; j++) {
            int2 e = cw[j];
            float2 zr = *((const float2*)(z + (size_t)e.x * EM) + c);
            float wv = __int_as_float(e.y);
            a0x = fmaf(wv, zr.x, a0x); a0y = fmaf(wv, zr.y, a0y);
        }
        float accx = (a0x + a1x) + (a2x + a3x);
        float accy = (a0y + a1y) + (a2y + a3y);
        float rc = 1.0f / (float)(end - start + 1);
        xx = sp(fmaf(accx * di, rc, bconv[2 * c]));
        xy = sp(fmaf(accy * di, rc, bconv[2 * c + 1]));
    }
    __syncthreads();      // sW ready
    lx[g][2 * c]     = xx;
    lx[g][2 * c + 1] = xy;
    __syncthreads();
    if (n < N) {
        float* xo = xout + (size_t)n * EM + 2 * c;
        if (mulW) {
            float ax = 0.0f, ay = 0.0f;
#pragma unroll
            for (int j = 0; j < EM; j++) {
                float lj = lx[g][j];
                ax = fmaf(lj, sW[j * EM + 2 * c], ax);
                ay = fmaf(lj, sW[j * EM + 2 * c + 1], ay);
            }
            xo[0] = ax * di;             // pre-scale layer-2 operand
            xo[1] = ay * di;
        } else {
            xo[0] = xx;
            xo[1] = xy;
        }
    }
}

// Kernel 7: dense heads: y = sp(x2 @ Wp1 + bp1); out = (y @ Wp2 + bp2)/sig.
__global__ __launch_bounds__(256) void node_out(
    const float* __restrict__ W_p1, const float* __restrict__ b_p1,
    const float* __restrict__ W_p2, const float* __restrict__ b_p2,
    const float* __restrict__ sig, const float* __restrict__ x2arr,
    float* __restrict__ out, int N)
{
    __shared__ float sP1[EM * EM];
    __shared__ float sbp1[EM];
    __shared__ float sP2[EM * ND];
    __shared__ float sbp2[ND];
    int t = threadIdx.x;
    sP1[t] = W_p1[t];
    if (t < EM)      sbp1[t] = b_p1[t];
    if (t < EM * ND) sP2[t] = W_p2[t];
    if (t < ND)      sbp2[t] = b_p2[t];
    __syncthreads();

    int n = blockIdx.x * 256 + t;
    if (n >= N) return;

    const float4* xp = (const float4*)(x2arr + (size_t)n * EM);
    float x2[EM];
#pragma unroll
    for (int q = 0; q < 4; q++) {
        float4 xv = xp[q];
        x2[4*q+0] = xv.x; x2[4*q+1] = xv.y; x2[4*q+2] = xv.z; x2[4*q+3] = xv.w;
    }
    float y[EM];
#pragma unroll
    for (int k = 0; k < EM; k++) {
        float a = sbp1[k];
#pragma unroll
        for (int j = 0; j < EM; j++) a = fmaf(x2[j], sP1[j * EM + k], a);
        y[k] = sp(a);
    }
    float rs = 1.0f / sig[n];
#pragma unroll
    for (int ch = 0; ch < ND; ch++) {
        float a = sbp2[ch];
#pragma unroll
        for (int j = 0; j < EM; j++) a = fmaf(y[j], sP2[j * ND + ch], a);
        out[(size_t)n * ND + ch] = a * rs;
    }
}

extern "C" void kernel_launch(void* const* d_in, const int* in_sizes, int n_in,
                              void* d_out, int out_size, void* d_ws, size_t ws_size,
                              hipStream_t stream) {
    const float* pos    = (const float*)d_in[0];
    const float* sig    = (const float*)d_in[1];
    const int*   ei     = (const int*)d_in[2];
    const float* W_init = (const float*)d_in[4];
    const float* b_init = (const float*)d_in[5];
    const float* W_g1   = (const float*)d_in[6];
    const float* b_g1   = (const float*)d_in[7];
    const float* W_g2   = (const float*)d_in[8];
    const float* b_g2   = (const float*)d_in[9];
    const float* W_p1   = (const float*)d_in[10];
    const float* b_p1   = (const float*)d_in[11];
    const float* W_p2   = (const float*)d_in[12];
    const float* b_p2   = (const float*)d_in[13];
    float* out = (float*)d_out;

    int N = in_sizes[0] / ND;
    int E = in_sizes[2] / 2;
    size_t Ns = (size_t)N, Es = (size_t)E;
    int NB = (N + BQ - 1) >> BQ_SH;   // <= MAXB for N <= 524288

    // Workspace layout (4B elements):
    // rowptr[N+1] | (pad to 8B) cw[E] (int2) | bcnt[1024] | gbase[1024]
    //   | gcur[1024] | dinv[N] | xwA[16N] | xwB[16N]
    // packed pairs[E] (u32, 32MB) aliases xwA (dead before node_init).
    int* rowptr = (int*)d_ws;
    size_t cwoff = (Ns + 2) & ~(size_t)1;     // even int offset -> 8B aligned
    int2* cw    = (int2*)((int*)d_ws + cwoff);
    int* bcnt   = (int*)(cw + Es);
    int* gbase  = bcnt + 1024;
    int* gcur   = gbase + 1024;
    size_t off  = cwoff + 2 * Es + 3 * 1024;
    off = (off + 3) & ~(size_t)3;
    float* dinv = (float*)d_ws + off;
    size_t offA = off + Ns;
    offA = (offA + 3) & ~(size_t)3;
    float* xwA  = (float*)d_ws + offA;
    float* xwB  = xwA + Ns * EM;
    unsigned int* pairs = (unsigned int*)xwA;

    int nbN = (N + 255) / 256;
    int nbG = (N + 15) / 16;            // deg_gather: 16 nodes/block
    int nbG2 = (N + 31) / 32;           // gather_conv: 32 nodes/block
    int nbBin = (E + CHK - 1) / CHK;

    bucket_zero<<<1, 1024, 0, stream>>>(bcnt);
    bucket_count<<<1024, 256, 0, stream>>>(ei, bcnt, E, NB);
    bucket_scan<<<1, 1024, 0, stream>>>(bcnt, gbase, gcur, NB);
    edge_bin<<<nbBin, 256, 0, stream>>>(ei, gcur, pairs, E);
    bucket_csr<<<NB, 256, 0, stream>>>(pairs, gbase, bcnt, rowptr, cw, N, NB);
    node_init<<<nbN, 256, 0, stream>>>(pos, W_init, b_init, W_g1, xwA, N);
    deg_gather<<<nbG, 256, 0, stream>>>(rowptr, cw, pos, dinv, xwA, N);
    gather_conv<<<nbG2, 256, 0, stream>>>(rowptr, cw, dinv, xwA, b_g1, W_g2, xwB, N, 1);
    gather_conv<<<nbG2, 256, 0, stream>>>(rowptr, cw, dinv, xwB, b_g2, W_g2, xwA, N, 0);
    node_out<<<nbN, 256, 0, stream>>>(W_p1, b_p1, W_p2, b_p2, sig, xwA, out, N);
}

// Round 7
// 784.460 us; speedup vs baseline: 1.1989x; 1.1989x over previous
//
#include <hip/hip_runtime.h>
#include <hip/hip_bf16.h>
#include <hip/hip_fp16.h>
#include <math.h>

// NODE_DIM=3, EMBED=16
#define ND 3
#define EM 16
#define BQ 512        // nodes per bucket (power of 2)
#define BQ_SH 9
#define MAXB 1024     // max buckets => supports N <= 524288
#define CHK 8192      // edges per edge_bin block (32 per thread)
#define COLS 12288    // LDS staging bound (mean bucket edges ~8192, +45 sigma)
// packed pair: (dst & 511) << 23 | src   (requires src < 2^23)
#define P_SH 23

__device__ __forceinline__ float sp(float x) {
    // jax.nn.softplus = max(x,0) + log1p(exp(-|x|))
    return fmaxf(x, 0.0f) + log1pf(expf(-fabsf(x)));
}

// Kernel 0: zero bucket counters.
__global__ __launch_bounds__(1024) void bucket_zero(int* __restrict__ bcnt)
{
    bcnt[threadIdx.x] = 0;
}

// Kernel A: bucket histogram of dst (bucket = dst >> 9). ONE pass over dst
// (32MB), LDS-aggregated, ~1k global atomics per block.
__global__ __launch_bounds__(256) void bucket_count(
    const int* __restrict__ ei, int* __restrict__ bcnt, int E, int NB)
{
    __shared__ int h[MAXB];
    int t = threadIdx.x;
    for (int i = t; i < MAXB; i += 256) h[i] = 0;
    __syncthreads();
    const int* dp = ei + (size_t)E;
    for (int e = blockIdx.x * 256 + t; e < E; e += gridDim.x * 256)
        atomicAdd(&h[((unsigned)dp[e]) >> BQ_SH], 1);
    __syncthreads();
    for (int i = t; i < NB; i += 256) {
        int v = h[i];
        if (v) atomicAdd(&bcnt[i], v);
    }
}

// Kernel B: exclusive scan of bucket counts (NB <= 1024) -> gbase, gcur.
__global__ __launch_bounds__(1024) void bucket_scan(
    const int* __restrict__ bcnt, int* __restrict__ gbase,
    int* __restrict__ gcur, int NB)
{
    __shared__ int sd[1024];
    int t = threadIdx.x;
    int v = (t < NB) ? bcnt[t] : 0;
    sd[t] = v;
    __syncthreads();
    for (int off = 1; off < 1024; off <<= 1) {
        int add = (t >= off) ? sd[t - off] : 0;
        __syncthreads();
        sd[t] += add;
        __syncthreads();
    }
    if (t < NB) { int ex = sd[t] - v; gbase[t] = ex; gcur[t] = ex; }
}

// Kernel C: bin edges into bucket-contiguous packed-pair runs, with the
// chunk SORTED IN LDS first so global writes are in-order & coalesced.
__global__ __launch_bounds__(256) void edge_bin(
    const int* __restrict__ ei, int* __restrict__ gcur,
    unsigned int* __restrict__ pairs, int E)
{
    __shared__ int lcnt[MAXB];            // histogram, then local cursor
    __shared__ int lbase[MAXB];           // local exclusive base
    __shared__ int sbase[MAXB];           // global run base
    __shared__ unsigned int stage[CHK];   // bucket-sorted packed payloads
    __shared__ unsigned short bid[CHK];   // bucket id per staged slot
    __shared__ int sd[256];
    int t = threadIdx.x;
    int c0 = blockIdx.x * CHK;
    int cntT = min(CHK, E - c0);
    for (int i = t; i < MAXB; i += 256) lcnt[i] = 0;
    __syncthreads();
    const int* dp = ei + (size_t)E;
    int dreg[32];
#pragma unroll
    for (int it = 0; it < 32; it++) {
        int e = c0 + it * 256 + t;
        dreg[it] = (e < E) ? dp[e] : 0;
        if (e < E) atomicAdd(&lcnt[((unsigned)dreg[it]) >> BQ_SH], 1);
    }
    __syncthreads();
    // exclusive scan of lcnt[1024] (4 per thread) -> lbase; reserve runs.
    int b4 = t * 4;
    int h0 = lcnt[b4], h1 = lcnt[b4 + 1], h2 = lcnt[b4 + 2], h3 = lcnt[b4 + 3];
    int s4 = h0 + h1 + h2 + h3;
    sd[t] = s4;
    __syncthreads();
    for (int off = 1; off < 256; off <<= 1) {
        int add = (t >= off) ? sd[t - off] : 0;
        __syncthreads();
        sd[t] += add;
        __syncthreads();
    }
    int ex = sd[t] - s4;
    lbase[b4]     = ex;
    lbase[b4 + 1] = ex + h0;
    lbase[b4 + 2] = ex + h0 + h1;
    lbase[b4 + 3] = ex + h0 + h1 + h2;
    sbase[b4]     = h0 ? atomicAdd(&gcur[b4], h0)     : 0;
    sbase[b4 + 1] = h1 ? atomicAdd(&gcur[b4 + 1], h1) : 0;
    sbase[b4 + 2] = h2 ? atomicAdd(&gcur[b4 + 2], h2) : 0;
    sbase[b4 + 3] = h3 ? atomicAdd(&gcur[b4 + 3], h3) : 0;
    lcnt[b4] = 0; lcnt[b4 + 1] = 0; lcnt[b4 + 2] = 0; lcnt[b4 + 3] = 0;
    __syncthreads();
    // scatter into LDS stage (bucket-sorted order)
#pragma unroll
    for (int it = 0; it < 32; it++) {
        int e = c0 + it * 256 + t;
        if (e < E) {
            int d = dreg[it];
            unsigned b = ((unsigned)d) >> BQ_SH;
            int s = ei[e];
            int pos = lbase[b] + atomicAdd(&lcnt[b], 1);
            stage[pos] = ((unsigned)(d & (BQ - 1)) << P_SH) | (unsigned)s;
            bid[pos] = (unsigned short)b;
        }
    }
    __syncthreads();
    // in-order write-out: consecutive threads -> consecutive addresses
    for (int i = t; i < cntT; i += 256) {
        unsigned b = bid[i];
        pairs[sbase[b] + (i - lbase[b])] = stage[i];
    }
}

// Kernel D (fused): per-bucket CSR build + edge weights + dinv.
// One block per bucket (512 nodes, ~8192 edges):
//  - pos[dst-bucket] staged in LDS (6KB)
//  - LDS per-node histogram -> scan -> rowptr (coalesced)
//  - scatter packed pairs into LDS staging (CSR order)
//  - flush: per edge gather pos[src] (6MB table, cache-friendly), compute
//    w = |pos[dst]-pos[src]|, write cw = {src,w} ONCE, fully coalesced;
//    accumulate per-node wsum in LDS -> dinv (coalesced).
__global__ __launch_bounds__(256) void bucket_csr(
    const unsigned int* __restrict__ pairs, const int* __restrict__ gbase,
    const int* __restrict__ bcnt, const float* __restrict__ pos,
    int* __restrict__ rowptr, int2* __restrict__ cw,
    float* __restrict__ dinv, int N, int NB)
{
    __shared__ int ncnt[BQ];
    __shared__ int ncur[BQ];
    __shared__ float wsum[BQ];
    __shared__ int sd[256];
    __shared__ unsigned int stg[COLS];
    __shared__ float posS[BQ * 3];
    int b = blockIdx.x;
    int t = threadIdx.x;
    int lo = b << BQ_SH;
    int hi = min(lo + BQ, N);
    int nloc = hi - lo;
    int r0 = gbase[b];
    int cntE = bcnt[b];
    for (int i = t; i < 3 * nloc; i += 256) posS[i] = pos[(size_t)lo * 3 + i];
    ncnt[2 * t] = 0;
    ncnt[2 * t + 1] = 0;
    wsum[2 * t] = 0.0f;
    wsum[2 * t + 1] = 0.0f;
    __syncthreads();
    for (int i = t; i < cntE; i += 256)
        atomicAdd(&ncnt[pairs[r0 + i] >> P_SH], 1);
    __syncthreads();
    // exclusive scan over 512 (2 per thread)
    int a0 = ncnt[2 * t], a1 = ncnt[2 * t + 1];
    int s2 = a0 + a1;
    sd[t] = s2;
    __syncthreads();
    for (int off = 1; off < 256; off <<= 1) {
        int add = (t >= off) ? sd[t - off] : 0;
        __syncthreads();
        sd[t] += add;
        __syncthreads();
    }
    int ex = sd[t] - s2;          // exclusive base for node 2t
    ncur[2 * t] = ex;
    ncur[2 * t + 1] = ex + a0;
    if (lo + 2 * t < hi)     rowptr[lo + 2 * t]     = r0 + ex;
    if (lo + 2 * t + 1 < hi) rowptr[lo + 2 * t + 1] = r0 + ex + a0;
    if (b == NB - 1 && t == 0) rowptr[N] = r0 + cntE;  // == E
    __syncthreads();
    bool fit = (cntE <= COLS);
    if (fit) {
        for (int i = t; i < cntE; i += 256) {
            unsigned p = pairs[r0 + i];
            int slot = atomicAdd(&ncur[p >> P_SH], 1);
            stg[slot] = p;
        }
        __syncthreads();
        for (int i = t; i < cntE; i += 256) {
            unsigned p = stg[i];
            int ldst = (int)(p >> P_SH);
            int src = (int)(p & ((1u << P_SH) - 1));
            float dx = posS[ldst * 3 + 0] - pos[(size_t)src * 3 + 0];
            float dy = posS[ldst * 3 + 1] - pos[(size_t)src * 3 + 1];
            float dz = posS[ldst * 3 + 2] - pos[(size_t)src * 3 + 2];
            float d = sqrtf(fmaf(dx, dx, fmaf(dy, dy, dz * dz)));
            cw[r0 + i] = make_int2(src, __float_as_int(d));
            atomicAdd(&wsum[ldst], d);
        }
    } else {
        // overflow fallback (practically unreachable): direct scatter
        for (int i = t; i < cntE; i += 256) {
            unsigned p = pairs[r0 + i];
            int ldst = (int)(p >> P_SH);
            int src = (int)(p & ((1u << P_SH) - 1));
            int slot = atomicAdd(&ncur[ldst], 1);
            float dx = posS[ldst * 3 + 0] - pos[(size_t)src * 3 + 0];
            float dy = posS[ldst * 3 + 1] - pos[(size_t)src * 3 + 1];
            float dz = posS[ldst * 3 + 2] - pos[(size_t)src * 3 + 2];
            float d = sqrtf(fmaf(dx, dx, fmaf(dy, dy, dz * dz)));
            cw[r0 + slot] = make_int2(src, __float_as_int(d));
            atomicAdd(&wsum[ldst], d);
        }
    }
    __syncthreads();
    for (int l = t; l < nloc; l += 256)
        dinv[lo + l] = rsqrtf(1.0f + wsum[l]);
}

// Kernel 1: x0 = softplus(pos @ W_init + b_init);
// zh1 = fp16( dinv[n] * (x0 @ W_g1) )  -- pre-scaled layer-1 operand.
__global__ __launch_bounds__(256) void node_init(
    const float* __restrict__ pos,
    const float* __restrict__ W_init, const float* __restrict__ b_init,
    const float* __restrict__ W_g1, const float* __restrict__ dinv,
    __half2* __restrict__ zh1, int N)
{
    __shared__ float sWi[ND * EM];
    __shared__ float sbi[EM];
    __shared__ float sW1[EM * EM];
    int t = threadIdx.x;
    if (t < ND * EM) sWi[t] = W_init[t];
    if (t < EM)      sbi[t] = b_init[t];
    sW1[t] = W_g1[t];
    __syncthreads();

    int n = blockIdx.x * 256 + t;
    if (n >= N) return;

    float p0 = pos[3 * (size_t)n + 0];
    float p1 = pos[3 * (size_t)n + 1];
    float p2 = pos[3 * (size_t)n + 2];

    float x0[EM];
#pragma unroll
    for (int j = 0; j < EM; j++) {
        float h = fmaf(p0, sWi[0 * EM + j],
                  fmaf(p1, sWi[1 * EM + j],
                  fmaf(p2, sWi[2 * EM + j], sbi[j])));
        x0[j] = sp(h);
    }
    float di = dinv[n];
    __half2* zo = zh1 + (size_t)n * 8;
#pragma unroll
    for (int k = 0; k < 8; k++) {
        float ax = 0.0f, ay = 0.0f;
#pragma unroll
        for (int j = 0; j < EM; j++) {
            ax = fmaf(x0[j], sW1[j * EM + 2 * k], ax);
            ay = fmaf(x0[j], sW1[j * EM + 2 * k + 1], ay);
        }
        zo[k] = __float22half2_rn(make_float2(ax * di, ay * di));
    }
}

// Kernel 6 (x2): fused GCN-mean layer on fp16 pre-scaled operand
// zh[s][c] = fp16(dinv[s]*x[s][c]). 8 lanes/node (lane = channel pair).
// Per edge per lane: one int2 cw load + one half2 z load; f32 accumulate.
// x = sp(di*acc/(deg+1)+b). mulW=1: zout = fp16((x@W)*di); else fout = x.
__global__ __launch_bounds__(256) void gather_conv(
    const int* __restrict__ rowptr, const int2* __restrict__ cw,
    const float* __restrict__ dinv, const __half2* __restrict__ zin,
    const float* __restrict__ bconv, const float* __restrict__ W,
    __half2* __restrict__ zout, float* __restrict__ fout, int N, int mulW)
{
    __shared__ float sW[EM * EM];
    __shared__ float lx[32][EM + 1];
    int t = threadIdx.x;
    sW[t] = W[t];
    int g = t >> 3, c = t & 7;          // 32 node groups, 8 lanes each
    int n = blockIdx.x * 32 + g;

    float xx = 0.0f, xy = 0.0f;
    float di = 1.0f;
    if (n < N) {
        int start = rowptr[n], end = rowptr[n + 1];
        di = dinv[n];
        float2 zv = __half22float2(zin[(size_t)n * 8 + c]);  // self loop
        float a0x = zv.x, a0y = zv.y;
        float a1x = 0.f, a1y = 0.f, a2x = 0.f, a2y = 0.f, a3x = 0.f, a3y = 0.f;
        int j = start;
        for (; j + 3 < end; j += 4) {
            int2 e0 = cw[j], e1 = cw[j + 1], e2 = cw[j + 2], e3 = cw[j + 3];
            float2 z0 = __half22float2(zin[(size_t)e0.x * 8 + c]);
            float2 z1 = __half22float2(zin[(size_t)e1.x * 8 + c]);
            float2 z2 = __half22float2(zin[(size_t)e2.x * 8 + c]);
            float2 z3 = __half22float2(zin[(size_t)e3.x * 8 + c]);
            float w0 = __int_as_float(e0.y), w1 = __int_as_float(e1.y);
            float w2 = __int_as_float(e2.y), w3 = __int_as_float(e3.y);
            a0x = fmaf(w0, z0.x, a0x); a0y = fmaf(w0, z0.y, a0y);
            a1x = fmaf(w1, z1.x, a1x); a1y = fmaf(w1, z1.y, a1y);
            a2x = fmaf(w2, z2.x, a2x); a2y = fmaf(w2, z2.y, a2y);
            a3x = fmaf(w3, z3.x, a3x); a3y = fmaf(w3, z3.y, a3y);
        }
        for (; j < end; j++) {
            int2 e = cw[j];
            float2 zr = __half22float2(zin[(size_t)e.x * 8 + c]);
            float wv = __int_as_float(e.y);
            a0x = fmaf(wv, zr.x, a0x); a0y = fmaf(wv, zr.y, a0y);
        }
        float accx = (a0x + a1x) + (a2x + a3x);
        float accy = (a0y + a1y) + (a2y + a3y);
        float rc = 1.0f / (float)(end - start + 1);
        xx = sp(fmaf(accx * di, rc, bconv[2 * c]));
        xy = sp(fmaf(accy * di, rc, bconv[2 * c + 1]));
    }
    __syncthreads();      // sW ready
    lx[g][2 * c]     = xx;
    lx[g][2 * c + 1] = xy;
    __syncthreads();
    if (n < N) {
        if (mulW) {
            float ax = 0.0f, ay = 0.0f;
#pragma unroll
            for (int j = 0; j < EM; j++) {
                float lj = lx[g][j];
                ax = fmaf(lj, sW[j * EM + 2 * c], ax);
                ay = fmaf(lj, sW[j * EM + 2 * c + 1], ay);
            }
            zout[(size_t)n * 8 + c] =
                __float22half2_rn(make_float2(ax * di, ay * di));
        } else {
            float* xo = fout + (size_t)n * EM + 2 * c;
            xo[0] = xx;
            xo[1] = xy;
        }
    }
}

// Kernel 7: dense heads: y = sp(x2 @ Wp1 + bp1); out = (y @ Wp2 + bp2)/sig.
__global__ __launch_bounds__(256) void node_out(
    const float* __restrict__ W_p1, const float* __restrict__ b_p1,
    const float* __restrict__ W_p2, const float* __restrict__ b_p2,
    const float* __restrict__ sig, const float* __restrict__ x2arr,
    float* __restrict__ out, int N)
{
    __shared__ float sP1[EM * EM];
    __shared__ float sbp1[EM];
    __shared__ float sP2[EM * ND];
    __shared__ float sbp2[ND];
    int t = threadIdx.x;
    sP1[t] = W_p1[t];
    if (t < EM)      sbp1[t] = b_p1[t];
    if (t < EM * ND) sP2[t] = W_p2[t];
    if (t < ND)      sbp2[t] = b_p2[t];
    __syncthreads();

    int n = blockIdx.x * 256 + t;
    if (n >= N) return;

    const float4* xp = (const float4*)(x2arr + (size_t)n * EM);
    float x2[EM];
#pragma unroll
    for (int q = 0; q < 4; q++) {
        float4 xv = xp[q];
        x2[4*q+0] = xv.x; x2[4*q+1] = xv.y; x2[4*q+2] = xv.z; x2[4*q+3] = xv.w;
    }
    float y[EM];
#pragma unroll
    for (int k = 0; k < EM; k++) {
        float a = sbp1[k];
#pragma unroll
        for (int j = 0; j < EM; j++) a = fmaf(x2[j], sP1[j * EM + k], a);
        y[k] = sp(a);
    }
    float rs = 1.0f / sig[n];
#pragma unroll
    for (int ch = 0; ch < ND; ch++) {
        float a = sbp2[ch];
#pragma unroll
        for (int j = 0; j < EM; j++) a = fmaf(y[j], sP2[j * ND + ch], a);
        out[(size_t)n * ND + ch] = a * rs;
    }
}

extern "C" void kernel_launch(void* const* d_in, const int* in_sizes, int n_in,
                              void* d_out, int out_size, void* d_ws, size_t ws_size,
                              hipStream_t stream) {
    const float* pos    = (const float*)d_in[0];
    const float* sig    = (const float*)d_in[1];
    const int*   ei     = (const int*)d_in[2];
    const float* W_init = (const float*)d_in[4];
    const float* b_init = (const float*)d_in[5];
    const float* W_g1   = (const float*)d_in[6];
    const float* b_g1   = (const float*)d_in[7];
    const float* W_g2   = (const float*)d_in[8];
    const float* b_g2   = (const float*)d_in[9];
    const float* W_p1   = (const float*)d_in[10];
    const float* b_p1   = (const float*)d_in[11];
    const float* W_p2   = (const float*)d_in[12];
    const float* b_p2   = (const float*)d_in[13];
    float* out = (float*)d_out;

    int N = in_sizes[0] / ND;
    int E = in_sizes[2] / 2;
    size_t Ns = (size_t)N, Es = (size_t)E;
    int NB = (N + BQ - 1) >> BQ_SH;   // <= MAXB for N <= 524288

    // Workspace layout (4B elements):
    // rowptr[N+1] | (pad to 8B) cw[E] (int2) | bcnt[1024] | gbase[1024]
    //   | gcur[1024] | dinv[N] | xf32[16N] | zh1[8N] | zh2[8N]
    // packed pairs[E] (u32, 32MB) aliases xf32 (dead before conv2 writes it).
    int* rowptr = (int*)d_ws;
    size_t cwoff = (Ns + 2) & ~(size_t)1;     // even int offset -> 8B aligned
    int2* cw    = (int2*)((int*)d_ws + cwoff);
    int* bcnt   = (int*)(cw + Es);
    int* gbase  = bcnt + 1024;
    int* gcur   = gbase + 1024;
    size_t off  = cwoff + 2 * Es + 3 * 1024;
    off = (off + 3) & ~(size_t)3;
    float* dinv = (float*)d_ws + off;
    size_t offA = off + Ns;
    offA = (offA + 3) & ~(size_t)3;
    float* xf32 = (float*)d_ws + offA;            // 16N f32
    __half2* zh1 = (__half2*)(xf32 + Ns * EM);    // 16N halfs = 8N words
    __half2* zh2 = (__half2*)((float*)(xf32 + Ns * EM) + Ns * 8);
    unsigned int* pairs = (unsigned int*)xf32;

    int nbN = (N + 255) / 256;
    int nbG2 = (N + 31) / 32;           // gather_conv: 32 nodes/block
    int nbBin = (E + CHK - 1) / CHK;

    bucket_zero<<<1, 1024, 0, stream>>>(bcnt);
    bucket_count<<<1024, 256, 0, stream>>>(ei, bcnt, E, NB);
    bucket_scan<<<1, 1024, 0, stream>>>(bcnt, gbase, gcur, NB);
    edge_bin<<<nbBin, 256, 0, stream>>>(ei, gcur, pairs, E);
    bucket_csr<<<NB, 256, 0, stream>>>(pairs, gbase, bcnt, pos, rowptr, cw, dinv, N, NB);
    node_init<<<nbN, 256, 0, stream>>>(pos, W_init, b_init, W_g1, dinv, zh1, N);
    gather_conv<<<nbG2, 256, 0, stream>>>(rowptr, cw, dinv, zh1, b_g1, W_g2, zh2, (float*)0, N, 1);
    gather_conv<<<nbG2, 256, 0, stream>>>(rowptr, cw, dinv, zh2, b_g2, W_g2, (__half2*)0, xf32, N, 0);
    node_out<<<nbN, 256, 0, stream>>>(W_p1, b_p1, W_p2, b_p2, sig, xf32, out, N);
}